// Round 2
// baseline (1752.923 us; speedup 1.0000x reference)
//
#include <hip/hip_runtime.h>

// Hetero-SAGE 2-layer forward, MI355X.
// Pipeline per launch:
//   CSR build (hist -> scan -> scatter) per direction, reused by both layers
//   layer0: agg (wave/dst-row) -> fused GEMM [agg,x]@[Wm;Ws]+b -> BN stats ->
//           BN+LeakyReLU+L2norm (fused, wave/row)
//   layer1: agg of h -> GEMM (in-place into d_out over agg) -> final L2norm
// agg buffers live in d_out (free scratch until the final GEMM).

#define NN 100000
#define EE 1600000

// ---------------- CSR build ----------------
__global__ void hist_kernel(const int* __restrict__ ei, int* __restrict__ cnt, int E) {
    int i = blockIdx.x * blockDim.x + threadIdx.x;
    if (i < E) atomicAdd(&cnt[ei[E + i]], 1);
}

__global__ void scan1(const int* __restrict__ cnt, int* __restrict__ part, int N) {
    __shared__ int s[256];
    int t = threadIdx.x;
    int base = blockIdx.x * 1024 + t * 4;
    int v = 0;
#pragma unroll
    for (int j = 0; j < 4; j++) { int idx = base + j; if (idx < N) v += cnt[idx]; }
    s[t] = v; __syncthreads();
    for (int d = 128; d > 0; d >>= 1) { if (t < d) s[t] += s[t + d]; __syncthreads(); }
    if (t == 0) part[blockIdx.x] = s[0];
}

__global__ void scan2(int* part, int* off_last, int nb) {
    __shared__ int s[128];
    int t = threadIdx.x;
    int v = (t < nb) ? part[t] : 0;
    s[t] = v; __syncthreads();
    for (int d = 1; d < 128; d <<= 1) {
        int x = (t >= d) ? s[t - d] : 0;
        __syncthreads();
        s[t] += x;
        __syncthreads();
    }
    if (t < nb) part[t] = s[t] - v;      // exclusive block offsets
    if (t == 127) *off_last = s[127];    // total edge count
}

__global__ void scan3(const int* __restrict__ cnt, const int* __restrict__ part,
                      int* __restrict__ off, int N) {
    __shared__ int s[256];
    int t = threadIdx.x;
    int base = blockIdx.x * 1024 + t * 4;
    int v[4]; int tv = 0;
#pragma unroll
    for (int j = 0; j < 4; j++) { int idx = base + j; v[j] = (idx < N) ? cnt[idx] : 0; tv += v[j]; }
    s[t] = tv; __syncthreads();
    for (int d = 1; d < 256; d <<= 1) {
        int x = (t >= d) ? s[t - d] : 0;
        __syncthreads();
        s[t] += x;
        __syncthreads();
    }
    int ex = s[t] - tv + part[blockIdx.x];
#pragma unroll
    for (int j = 0; j < 4; j++) { int idx = base + j; if (idx < N) { off[idx] = ex; ex += v[j]; } }
}

__global__ void scatter_kernel(const int* __restrict__ ei, int* __restrict__ cur,
                               int* __restrict__ srcs, int E) {
    int i = blockIdx.x * blockDim.x + threadIdx.x;
    if (i < E) {
        int s = ei[i];
        int d = ei[E + i];
        int p = atomicAdd(&cur[d], 1);
        srcs[p] = s;
    }
}

// ---------------- mean aggregation: one wave per dst row ----------------
__global__ void agg_kernel(const float* __restrict__ xsrc, const int* __restrict__ srcs,
                           const int* __restrict__ off, float* __restrict__ out, int N) {
    int w = blockIdx.x * 4 + (threadIdx.x >> 6);
    if (w >= N) return;
    int lane = threadIdx.x & 63;
    int o0 = off[w], o1 = off[w + 1];
    const float2* X = (const float2*)xsrc;
    float ax0 = 0.f, ay0 = 0.f, ax1 = 0.f, ay1 = 0.f;
    int e = o0;
    for (; e + 2 <= o1; e += 2) {
        int s0 = srcs[e], s1 = srcs[e + 1];
        float2 v0 = X[(size_t)s0 * 64 + lane];
        float2 v1 = X[(size_t)s1 * 64 + lane];
        ax0 += v0.x; ay0 += v0.y;
        ax1 += v1.x; ay1 += v1.y;
    }
    if (e < o1) {
        int s0 = srcs[e];
        float2 v0 = X[(size_t)s0 * 64 + lane];
        ax0 += v0.x; ay0 += v0.y;
    }
    float inv = 1.0f / fmaxf((float)(o1 - o0), 1.0f);
    float2 r; r.x = (ax0 + ax1) * inv; r.y = (ay0 + ay1) * inv;
    ((float2*)out)[(size_t)w * 64 + lane] = r;
}

// ---------------- fused GEMM: out = A1@W1 + A2@W2 + bias ----------------
// A1,A2: [M,128] f32; W1,W2: [128,128] row-major; tile M=64 x N=128, KC=16
__global__ __launch_bounds__(256) void gemm_kernel(
        const float* __restrict__ A1, const float* __restrict__ A2,
        const float* __restrict__ W1, const float* __restrict__ W2,
        const float* __restrict__ bias, float* __restrict__ out, int M) {
    __shared__ float As[16][68];    // [k][m] transposed, +4 pad (16B-aligned rows)
    __shared__ float Ws[16][132];   // [k][n], +4 pad
    int t = threadIdx.x;
    int m0 = blockIdx.x * 64;
    int tn = t & 31;   // n base = tn*4
    int tm = t >> 5;   // m base = tm*8

    float acc[8][4];
#pragma unroll
    for (int i = 0; i < 8; i++)
#pragma unroll
        for (int j = 0; j < 4; j++) acc[i][j] = 0.f;

    int am = t >> 2;         // staging row 0..63
    int ak = (t & 3) * 4;    // staging k base

    for (int ch = 0; ch < 16; ch++) {
        const float* A = (ch < 8) ? A1 : A2;
        const float* W = (ch < 8) ? W1 : W2;
        int kc = (ch & 7) * 16;
        int mrow = m0 + am; if (mrow >= M) mrow = M - 1;
        float4 av = *(const float4*)&A[(size_t)mrow * 128 + kc + ak];
        int f0 = t, f1 = t + 256;
        float4 wv0 = *(const float4*)&W[(size_t)(kc + (f0 >> 5)) * 128 + (f0 & 31) * 4];
        float4 wv1 = *(const float4*)&W[(size_t)(kc + (f1 >> 5)) * 128 + (f1 & 31) * 4];
        __syncthreads();   // protect previous iteration's LDS reads
        As[ak + 0][am] = av.x; As[ak + 1][am] = av.y;
        As[ak + 2][am] = av.z; As[ak + 3][am] = av.w;
        *(float4*)&Ws[f0 >> 5][(f0 & 31) * 4] = wv0;
        *(float4*)&Ws[f1 >> 5][(f1 & 31) * 4] = wv1;
        __syncthreads();
#pragma unroll
        for (int kk = 0; kk < 16; kk++) {
            float4 a0 = *(const float4*)&As[kk][tm * 8];
            float4 a1 = *(const float4*)&As[kk][tm * 8 + 4];
            float4 w  = *(const float4*)&Ws[kk][tn * 4];
            float a[8] = {a0.x, a0.y, a0.z, a0.w, a1.x, a1.y, a1.z, a1.w};
#pragma unroll
            for (int i = 0; i < 8; i++) {
                acc[i][0] += a[i] * w.x;
                acc[i][1] += a[i] * w.y;
                acc[i][2] += a[i] * w.z;
                acc[i][3] += a[i] * w.w;
            }
        }
    }
    float4 bv = *(const float4*)&bias[tn * 4];
#pragma unroll
    for (int i = 0; i < 8; i++) {
        int m = m0 + tm * 8 + i;
        if (m < M) {
            float4 o;
            o.x = acc[i][0] + bv.x; o.y = acc[i][1] + bv.y;
            o.z = acc[i][2] + bv.z; o.w = acc[i][3] + bv.w;
            *(float4*)&out[(size_t)m * 128 + tn * 4] = o;
        }
    }
}

// ---------------- BatchNorm statistics ----------------
__global__ void bn_stats(const float* __restrict__ h, float* __restrict__ part, int N) {
    int t = threadIdx.x;
    int c = t & 127;
    int rh = t >> 7;  // 0/1
    float s = 0.f, q = 0.f;
    for (int r = blockIdx.x * 2 + rh; r < N; r += gridDim.x * 2) {
        float v = h[(size_t)r * 128 + c];
        s += v; q += v * v;
    }
    __shared__ float ls[256];
    ls[t] = s; __syncthreads();
    if (t < 128) ls[t] += ls[t + 128];
    __syncthreads();
    if (t < 128) part[(size_t)blockIdx.x * 256 + t] = ls[t];
    __syncthreads();
    ls[t] = q; __syncthreads();
    if (t < 128) ls[t] += ls[t + 128];
    __syncthreads();
    if (t < 128) part[(size_t)blockIdx.x * 256 + 128 + t] = ls[t];
}

__global__ void bn_reduce(const float* __restrict__ part, float* __restrict__ stat, int nb) {
    int t = threadIdx.x;  // 256
    float s = 0.f;
    for (int b = 0; b < nb; b++) s += part[(size_t)b * 256 + t];
    stat[t] = s;
}

// ---------------- fused BN + LeakyReLU + row L2 norm (wave per row) ----------------
__global__ void bn_apply(float* __restrict__ h, const float* __restrict__ stat,
                         const float* __restrict__ g, const float* __restrict__ be, int N) {
    int w = blockIdx.x * 4 + (threadIdx.x >> 6);
    if (w >= N) return;
    int lane = threadIdx.x & 63;
    int c0 = lane * 2;
    float invN = 1.0f / (float)N;
    float mu0 = stat[c0] * invN, mu1 = stat[c0 + 1] * invN;
    float v0 = stat[128 + c0] * invN - mu0 * mu0;
    float v1 = stat[128 + c0 + 1] * invN - mu1 * mu1;
    float rs0 = rsqrtf(v0 + 1e-5f), rs1 = rsqrtf(v1 + 1e-5f);
    float g0 = g[c0], g1 = g[c0 + 1], b0 = be[c0], b1 = be[c0 + 1];
    float2 x = ((float2*)h)[(size_t)w * 64 + lane];
    float y0 = (x.x - mu0) * rs0 * g0 + b0;
    float y1 = (x.y - mu1) * rs1 * g1 + b1;
    y0 = (y0 >= 0.f) ? y0 : 0.01f * y0;
    y1 = (y1 >= 0.f) ? y1 : 0.01f * y1;
    float q = y0 * y0 + y1 * y1;
#pragma unroll
    for (int d = 1; d < 64; d <<= 1) q += __shfl_xor(q, d);
    float inv = 1.0f / fmaxf(sqrtf(q), 1e-12f);
    float2 r; r.x = y0 * inv; r.y = y1 * inv;
    ((float2*)h)[(size_t)w * 64 + lane] = r;
}

// ---------------- plain row L2 norm (wave per row) ----------------
__global__ void l2_kernel(float* __restrict__ o, int N) {
    int w = blockIdx.x * 4 + (threadIdx.x >> 6);
    if (w >= N) return;
    int lane = threadIdx.x & 63;
    float2 x = ((float2*)o)[(size_t)w * 64 + lane];
    float q = x.x * x.x + x.y * x.y;
#pragma unroll
    for (int d = 1; d < 64; d <<= 1) q += __shfl_xor(q, d);
    float inv = 1.0f / fmaxf(sqrtf(q), 1e-12f);
    x.x *= inv; x.y *= inv;
    ((float2*)o)[(size_t)w * 64 + lane] = x;
}

extern "C" void kernel_launch(void* const* d_in, const int* in_sizes, int n_in,
                              void* d_out, int out_size, void* d_ws, size_t ws_size,
                              hipStream_t stream) {
    const float* x_a    = (const float*)d_in[0];
    const float* x_b    = (const float*)d_in[1];
    const int*   ei_ab  = (const int*)d_in[2];
    const int*   ei_ba  = (const int*)d_in[3];
    const float* W0ab_m = (const float*)d_in[4];
    const float* b0ab   = (const float*)d_in[5];
    const float* W0ab_s = (const float*)d_in[6];
    const float* W0ba_m = (const float*)d_in[7];
    const float* b0ba   = (const float*)d_in[8];
    const float* W0ba_s = (const float*)d_in[9];
    const float* g0a    = (const float*)d_in[10];
    const float* be0a   = (const float*)d_in[11];
    const float* g0b    = (const float*)d_in[12];
    const float* be0b   = (const float*)d_in[13];
    const float* W1ab_m = (const float*)d_in[14];
    const float* b1ab   = (const float*)d_in[15];
    const float* W1ab_s = (const float*)d_in[16];
    const float* W1ba_m = (const float*)d_in[17];
    const float* b1ba   = (const float*)d_in[18];
    const float* W1ba_s = (const float*)d_in[19];

    char* ws = (char*)d_ws;
    size_t p = 0;
    auto alloc = [&](size_t bytes) -> char* {
        char* r = ws + p;
        p += (bytes + 255) & ~(size_t)255;
        return r;
    };
    float* h_a     = (float*)alloc((size_t)NN * 128 * 4);
    float* h_b     = (float*)alloc((size_t)NN * 128 * 4);
    int*   off_ab  = (int*)alloc((NN + 1) * 4);
    int*   off_ba  = (int*)alloc((NN + 1) * 4);
    int*   cnt_ab  = (int*)alloc(NN * 4);   // later reused as scatter cursor
    int*   cnt_ba  = (int*)alloc(NN * 4);
    int*   srcs_ab = (int*)alloc((size_t)EE * 4);
    int*   srcs_ba = (int*)alloc((size_t)EE * 4);
    int*   part_ab = (int*)alloc(1024);
    int*   part_ba = (int*)alloc(1024);
    float* bnpart  = (float*)alloc(200 * 256 * 4);
    float* stat    = (float*)alloc(256 * 4);

    float* agg_a = (float*)d_out;                       // [NN,128] scratch in output
    float* agg_b = (float*)d_out + (size_t)NN * 128;

    // ---- CSR build (both directions) ----
    hipMemsetAsync(cnt_ab, 0, NN * 4, stream);
    hipMemsetAsync(cnt_ba, 0, NN * 4, stream);
    hist_kernel<<<6250, 256, 0, stream>>>(ei_ab, cnt_ab, EE);
    hist_kernel<<<6250, 256, 0, stream>>>(ei_ba, cnt_ba, EE);
    scan1<<<98, 256, 0, stream>>>(cnt_ab, part_ab, NN);
    scan1<<<98, 256, 0, stream>>>(cnt_ba, part_ba, NN);
    scan2<<<1, 128, 0, stream>>>(part_ab, off_ab + NN, 98);
    scan2<<<1, 128, 0, stream>>>(part_ba, off_ba + NN, 98);
    scan3<<<98, 256, 0, stream>>>(cnt_ab, part_ab, off_ab, NN);
    scan3<<<98, 256, 0, stream>>>(cnt_ba, part_ba, off_ba, NN);
    hipMemcpyAsync(cnt_ab, off_ab, NN * 4, hipMemcpyDeviceToDevice, stream);
    hipMemcpyAsync(cnt_ba, off_ba, NN * 4, hipMemcpyDeviceToDevice, stream);
    scatter_kernel<<<6250, 256, 0, stream>>>(ei_ab, cnt_ab, srcs_ab, EE);
    scatter_kernel<<<6250, 256, 0, stream>>>(ei_ba, cnt_ba, srcs_ba, EE);

    // ---- layer 0 ----
    agg_kernel<<<25000, 256, 0, stream>>>(x_b, srcs_ba, off_ba, agg_a, NN);
    agg_kernel<<<25000, 256, 0, stream>>>(x_a, srcs_ab, off_ab, agg_b, NN);
    gemm_kernel<<<1563, 256, 0, stream>>>(agg_a, x_a, W0ba_m, W0ba_s, b0ba, h_a, NN);
    gemm_kernel<<<1563, 256, 0, stream>>>(agg_b, x_b, W0ab_m, W0ab_s, b0ab, h_b, NN);
    bn_stats<<<200, 256, 0, stream>>>(h_a, bnpart, NN);
    bn_reduce<<<1, 256, 0, stream>>>(bnpart, stat, 200);
    bn_apply<<<25000, 256, 0, stream>>>(h_a, stat, g0a, be0a, NN);
    bn_stats<<<200, 256, 0, stream>>>(h_b, bnpart, NN);
    bn_reduce<<<1, 256, 0, stream>>>(bnpart, stat, 200);
    bn_apply<<<25000, 256, 0, stream>>>(h_b, stat, g0b, be0b, NN);

    // ---- layer 1 (GEMM writes d_out in place over its own agg rows: safe,
    //      each block reads only its own A1 rows before its epilogue store) ----
    agg_kernel<<<25000, 256, 0, stream>>>(h_b, srcs_ba, off_ba, agg_a, NN);
    agg_kernel<<<25000, 256, 0, stream>>>(h_a, srcs_ab, off_ab, agg_b, NN);
    gemm_kernel<<<1563, 256, 0, stream>>>(agg_a, h_a, W1ba_m, W1ba_s, b1ba, agg_a, NN);
    gemm_kernel<<<1563, 256, 0, stream>>>(agg_b, h_b, W1ab_m, W1ab_s, b1ab, agg_b, NN);
    l2_kernel<<<50000, 256, 0, stream>>>((float*)d_out, 2 * NN);
}

// Round 4
// 1447.658 us; speedup vs baseline: 1.2109x; 1.2109x over previous
//
#include <hip/hip_runtime.h>

// Hetero-SAGE 2-layer forward, MI355X — bf16 data path + MFMA GEMM.
// Storage bf16 (x, agg, h, W), compute fp32 (MFMA accum, BN, L2 norms).
// CSR build uses a 2-pass bucketed scatter to kill 4B-random-write line
// amplification (round-2 rocprof: WRITE_SIZE 106MB for 6.4MB payload).

#define NN 100000
#define EE 1600000
#define NB 3125          // dst buckets of 32 rows each (100000/32)

typedef unsigned int uint32;
typedef __attribute__((ext_vector_type(8))) short short8;
typedef __attribute__((ext_vector_type(4))) float f32x4;

__device__ __forceinline__ unsigned short f2bf(float f) {
    unsigned u = __float_as_uint(f);
    return (unsigned short)((u + 0x7fffu + ((u >> 16) & 1u)) >> 16);  // RNE
}
__device__ __forceinline__ uint32 pk2(float a, float b) {
    return (uint32)f2bf(a) | ((uint32)f2bf(b) << 16);
}
__device__ __forceinline__ float bl(uint32 u) { return __uint_as_float(u << 16); }
__device__ __forceinline__ float bh(uint32 u) { return __uint_as_float(u & 0xffff0000u); }

// ---------------- prep: fp32 -> bf16 (8 elems/thread) ----------------
__global__ void f2b_kernel(const float* __restrict__ src, unsigned short* __restrict__ dst, int n8) {
    int i = blockIdx.x * 256 + threadIdx.x;
    if (i >= n8) return;
    float4 v0 = ((const float4*)src)[(size_t)i * 2];
    float4 v1 = ((const float4*)src)[(size_t)i * 2 + 1];
    uint4 o;
    o.x = pk2(v0.x, v0.y); o.y = pk2(v0.z, v0.w);
    o.z = pk2(v1.x, v1.y); o.w = pk2(v1.z, v1.w);
    ((uint4*)dst)[i] = o;
}

// ---------------- prep: W[k][n] fp32 -> Wt[n][k] bf16, 8 matrices ----------------
__global__ void prep_w(const float* w0, const float* w1, const float* w2, const float* w3,
                       const float* w4, const float* w5, const float* w6, const float* w7,
                       unsigned short* __restrict__ wt) {
    const float* ws[8] = {w0, w1, w2, w3, w4, w5, w6, w7};
    const float* W = ws[blockIdx.y];
    unsigned short* Wt = wt + (size_t)blockIdx.y * 16384;
    int idx = blockIdx.x * 256 + threadIdx.x;   // 64 x-blocks * 256 = 16384
    int n = idx >> 7, k = idx & 127;
    Wt[n * 128 + k] = f2bf(W[(size_t)k * 128 + n]);
}

// ---------------- CSR build ----------------
__global__ void hist_kernel(const int* __restrict__ ei, int* __restrict__ cnt, int E) {
    int i = blockIdx.x * blockDim.x + threadIdx.x;
    if (i < E) atomicAdd(&cnt[ei[E + i]], 1);
}

__global__ void scan1(const int* __restrict__ cnt, int* __restrict__ part, int N) {
    __shared__ int s[256];
    int t = threadIdx.x;
    int base = blockIdx.x * 1024 + t * 4;
    int v = 0;
#pragma unroll
    for (int j = 0; j < 4; j++) { int idx = base + j; if (idx < N) v += cnt[idx]; }
    s[t] = v; __syncthreads();
    for (int d = 128; d > 0; d >>= 1) { if (t < d) s[t] += s[t + d]; __syncthreads(); }
    if (t == 0) part[blockIdx.x] = s[0];
}

__global__ void scan2(int* part, int* off_last, int nb) {
    __shared__ int s[128];
    int t = threadIdx.x;
    int v = (t < nb) ? part[t] : 0;
    s[t] = v; __syncthreads();
    for (int d = 1; d < 128; d <<= 1) {
        int x = (t >= d) ? s[t - d] : 0;
        __syncthreads();
        s[t] += x;
        __syncthreads();
    }
    if (t < nb) part[t] = s[t] - v;
    if (t == 127) *off_last = s[127];
}

__global__ void scan3(const int* __restrict__ cnt, const int* __restrict__ part,
                      int* __restrict__ off, int N) {
    __shared__ int s[256];
    int t = threadIdx.x;
    int base = blockIdx.x * 1024 + t * 4;
    int v[4]; int tv = 0;
#pragma unroll
    for (int j = 0; j < 4; j++) { int idx = base + j; v[j] = (idx < N) ? cnt[idx] : 0; tv += v[j]; }
    s[t] = tv; __syncthreads();
    for (int d = 1; d < 256; d <<= 1) {
        int x = (t >= d) ? s[t - d] : 0;
        __syncthreads();
        s[t] += x;
        __syncthreads();
    }
    int ex = s[t] - tv + part[blockIdx.x];
#pragma unroll
    for (int j = 0; j < 4; j++) { int idx = base + j; if (idx < N) { off[idx] = ex; ex += v[j]; } }
}

__global__ void bcur_init(const int* __restrict__ off, int* __restrict__ bcur) {
    int b = blockIdx.x * 256 + threadIdx.x;
    if (b < NB) bcur[b * 16] = off[b * 32];   // one cursor per 64B line
}

// pass A: append (src,dst) to dst-range bucket region (line-local 8B writes)
__global__ void bucketA(const int* __restrict__ ei, int* __restrict__ bcur,
                        uint2* __restrict__ tmp, int E) {
    int i = blockIdx.x * blockDim.x + threadIdx.x;
    if (i < E) {
        int s = ei[i];
        int d = ei[E + i];
        int p = atomicAdd(&bcur[(d >> 5) * 16], 1);
        uint2 v; v.x = (uint32)s; v.y = (uint32)d;
        tmp[p] = v;
    }
}

// pass B: exact per-dst scatter; writes land within ~2KB bucket windows
__global__ void bucketB(const uint2* __restrict__ tmp, int* __restrict__ cur,
                        int* __restrict__ srcs, int E) {
    int i = blockIdx.x * blockDim.x + threadIdx.x;
    if (i < E) {
        uint2 v = tmp[i];
        int q = atomicAdd(&cur[v.y], 1);
        srcs[q] = (int)v.x;
    }
}

// ---------------- mean aggregation (bf16 src/dst): one wave per dst row ----------------
__global__ void agg_kernel(const uint32* __restrict__ Xu, const int* __restrict__ srcs,
                           const int* __restrict__ off, uint32* __restrict__ out, int N) {
    int w = blockIdx.x * 4 + (threadIdx.x >> 6);
    if (w >= N) return;
    int lane = threadIdx.x & 63;
    int o0 = off[w], o1 = off[w + 1];
    float ax0 = 0.f, ay0 = 0.f, ax1 = 0.f, ay1 = 0.f;
    int e = o0;
    for (; e + 2 <= o1; e += 2) {
        uint32 v0 = Xu[(size_t)srcs[e] * 64 + lane];
        uint32 v1 = Xu[(size_t)srcs[e + 1] * 64 + lane];
        ax0 += bl(v0); ay0 += bh(v0);
        ax1 += bl(v1); ay1 += bh(v1);
    }
    if (e < o1) {
        uint32 v0 = Xu[(size_t)srcs[e] * 64 + lane];
        ax0 += bl(v0); ay0 += bh(v0);
    }
    float inv = 1.0f / fmaxf((float)(o1 - o0), 1.0f);
    out[(size_t)w * 64 + lane] = pk2((ax0 + ax1) * inv, (ay0 + ay1) * inv);
}

// ---------------- MFMA GEMM: out = A1@W1 + A2@W2 + bias ----------------
// A1,A2: [M][128] bf16; Wt1,Wt2: [128 n][128 k] bf16 (pre-transposed).
// Block: 256 thr = 4 waves (2x2), tile 128m x 128n, BK=64, 4 K-steps.
// LDS XOR-swizzle (G4): byte ^= ((row&7)<<4) -> conflict-free ds_read_b128.
template<bool OBF>
__global__ __launch_bounds__(256) void gemm_bf16(
        const unsigned short* __restrict__ A1, const unsigned short* __restrict__ A2,
        const unsigned short* __restrict__ Wt1, const unsigned short* __restrict__ Wt2,
        const float* __restrict__ bias, void* __restrict__ outp, int M) {
    __shared__ unsigned short As[128 * 64];
    __shared__ unsigned short Bs[128 * 64];
    int t = threadIdx.x;
    int m0 = blockIdx.x * 128;
    int lane = t & 63;
    int wid = t >> 6;
    int wr = wid >> 1, wc = wid & 1;

    f32x4 acc[4][4];
#pragma unroll
    for (int i = 0; i < 4; i++)
#pragma unroll
        for (int j = 0; j < 4; j++) acc[i][j] = (f32x4){0.f, 0.f, 0.f, 0.f};

    int rs = t >> 3;     // staging row base 0..31
    int gs = t & 7;      // staging 16B k-group
    uint4 arg[2][4], brg[2][4];

    // prologue: load + write K-step 0  (A1, kc=0)
#pragma unroll
    for (int j = 0; j < 4; j++) {
        int row = rs + j * 32;
        int mrow = m0 + row; if (mrow >= M) mrow = M - 1;
        arg[0][j] = *(const uint4*)&A1[(size_t)mrow * 128 + gs * 8];
        brg[0][j] = *(const uint4*)&Wt1[(size_t)row * 128 + gs * 8];
    }
#pragma unroll
    for (int j = 0; j < 4; j++) {
        int row = rs + j * 32;
        int o = row * 64 + ((gs ^ (row & 7)) << 3);
        *(uint4*)&As[o] = arg[0][j];
        *(uint4*)&Bs[o] = brg[0][j];
    }
    __syncthreads();

    for (int ks = 0; ks < 4; ks++) {
        int nxt = (ks + 1) & 1;
        if (ks < 3) {  // prefetch next step's global tiles into regs
            const unsigned short* A  = (ks >= 1) ? A2 : A1;
            const unsigned short* Wt = (ks >= 1) ? Wt2 : Wt1;
            int kc = ((ks + 1) & 1) * 64;
#pragma unroll
            for (int j = 0; j < 4; j++) {
                int row = rs + j * 32;
                int mrow = m0 + row; if (mrow >= M) mrow = M - 1;
                arg[nxt][j] = *(const uint4*)&A[(size_t)mrow * 128 + kc + gs * 8];
                brg[nxt][j] = *(const uint4*)&Wt[(size_t)row * 128 + kc + gs * 8];
            }
        }
        // compute current K-step (64 k = 2 MFMA k-slices)
#pragma unroll
        for (int kk = 0; kk < 2; kk++) {
            short8 af[4], bfr[4];
            int g = kk * 4 + (lane >> 4);
#pragma unroll
            for (int x = 0; x < 4; x++) {
                int row = wr * 64 + x * 16 + (lane & 15);
                af[x] = *(const short8*)&As[row * 64 + ((g ^ (row & 7)) << 3)];
                int nr = wc * 64 + x * 16 + (lane & 15);
                bfr[x] = *(const short8*)&Bs[nr * 64 + ((g ^ (nr & 7)) << 3)];
            }
#pragma unroll
            for (int mi = 0; mi < 4; mi++)
#pragma unroll
                for (int ni = 0; ni < 4; ni++)
                    acc[mi][ni] = __builtin_amdgcn_mfma_f32_16x16x32_bf16(
                        af[mi], bfr[ni], acc[mi][ni], 0, 0, 0);
        }
        __syncthreads();
        if (ks < 3) {
#pragma unroll
            for (int j = 0; j < 4; j++) {
                int row = rs + j * 32;
                int o = row * 64 + ((gs ^ (row & 7)) << 3);
                *(uint4*)&As[o] = arg[nxt][j];
                *(uint4*)&Bs[o] = brg[nxt][j];
            }
            __syncthreads();
        }
    }

    float br_[4];
#pragma unroll
    for (int ni = 0; ni < 4; ni++) br_[ni] = bias[wc * 64 + ni * 16 + (lane & 15)];
#pragma unroll
    for (int mi = 0; mi < 4; mi++) {
        int mbase = m0 + wr * 64 + mi * 16 + ((lane >> 4) << 2);
#pragma unroll
        for (int i = 0; i < 4; i++) {
            int m = mbase + i;
            if (m < M) {
#pragma unroll
                for (int ni = 0; ni < 4; ni++) {
                    int n = wc * 64 + ni * 16 + (lane & 15);
                    float v = acc[mi][ni][i] + br_[ni];
                    if (OBF) ((unsigned short*)outp)[(size_t)m * 128 + n] = f2bf(v);
                    else     ((float*)outp)[(size_t)m * 128 + n] = v;
                }
            }
        }
    }
}

// ---------------- BatchNorm statistics over bf16 h ----------------
__global__ void bn_stats(const uint32* __restrict__ h, float* __restrict__ part, int N) {
    int t = threadIdx.x;
    int p = t & 63;       // col-pair (2 bf16 per uint)
    int rh = t >> 6;      // 4 row groups
    float s0 = 0.f, s1 = 0.f, q0 = 0.f, q1 = 0.f;
    for (int r = blockIdx.x * 4 + rh; r < N; r += gridDim.x * 4) {
        uint32 v = h[(size_t)r * 64 + p];
        float x0 = bl(v), x1 = bh(v);
        s0 += x0; s1 += x1; q0 += x0 * x0; q1 += x1 * x1;
    }
    __shared__ float ls[256];
    float* po = &part[(size_t)blockIdx.x * 256];
    ls[t] = s0; __syncthreads();
    if (t < 64) po[2 * t] = ls[t] + ls[t + 64] + ls[t + 128] + ls[t + 192];
    __syncthreads();
    ls[t] = s1; __syncthreads();
    if (t < 64) po[2 * t + 1] = ls[t] + ls[t + 64] + ls[t + 128] + ls[t + 192];
    __syncthreads();
    ls[t] = q0; __syncthreads();
    if (t < 64) po[128 + 2 * t] = ls[t] + ls[t + 64] + ls[t + 128] + ls[t + 192];
    __syncthreads();
    ls[t] = q1; __syncthreads();
    if (t < 64) po[128 + 2 * t + 1] = ls[t] + ls[t + 64] + ls[t + 128] + ls[t + 192];
}

__global__ void bn_reduce(const float* __restrict__ part, float* __restrict__ stat, int nb) {
    int t = threadIdx.x;  // 256
    float s = 0.f;
    for (int b = 0; b < nb; b++) s += part[(size_t)b * 256 + t];
    stat[t] = s;
}

// ---------------- fused BN + LeakyReLU + row L2 norm (bf16 in/out) ----------------
__global__ void bn_apply(uint32* __restrict__ h, const float* __restrict__ stat,
                         const float* __restrict__ g, const float* __restrict__ be, int N) {
    int w = blockIdx.x * 4 + (threadIdx.x >> 6);
    if (w >= N) return;
    int lane = threadIdx.x & 63;
    int c0 = lane * 2;
    float invN = 1.0f / (float)N;
    float mu0 = stat[c0] * invN, mu1 = stat[c0 + 1] * invN;
    float v0 = stat[128 + c0] * invN - mu0 * mu0;
    float v1 = stat[128 + c0 + 1] * invN - mu1 * mu1;
    float rs0 = rsqrtf(v0 + 1e-5f), rs1 = rsqrtf(v1 + 1e-5f);
    float g0 = g[c0], g1 = g[c0 + 1], b0 = be[c0], b1 = be[c0 + 1];
    uint32 xv = h[(size_t)w * 64 + lane];
    float y0 = (bl(xv) - mu0) * rs0 * g0 + b0;
    float y1 = (bh(xv) - mu1) * rs1 * g1 + b1;
    y0 = (y0 >= 0.f) ? y0 : 0.01f * y0;
    y1 = (y1 >= 0.f) ? y1 : 0.01f * y1;
    float q = y0 * y0 + y1 * y1;
#pragma unroll
    for (int d = 1; d < 64; d <<= 1) q += __shfl_xor(q, d);
    float inv = 1.0f / fmaxf(sqrtf(q), 1e-12f);
    h[(size_t)w * 64 + lane] = pk2(y0 * inv, y1 * inv);
}

// ---------------- plain row L2 norm (fp32 d_out) ----------------
__global__ void l2_kernel(float* __restrict__ o, int N) {
    int w = blockIdx.x * 4 + (threadIdx.x >> 6);
    if (w >= N) return;
    int lane = threadIdx.x & 63;
    float2 x = ((float2*)o)[(size_t)w * 64 + lane];
    float q = x.x * x.x + x.y * x.y;
#pragma unroll
    for (int d = 1; d < 64; d <<= 1) q += __shfl_xor(q, d);
    float inv = 1.0f / fmaxf(sqrtf(q), 1e-12f);
    x.x *= inv; x.y *= inv;
    ((float2*)o)[(size_t)w * 64 + lane] = x;
}

extern "C" void kernel_launch(void* const* d_in, const int* in_sizes, int n_in,
                              void* d_out, int out_size, void* d_ws, size_t ws_size,
                              hipStream_t stream) {
    const float* x_a    = (const float*)d_in[0];
    const float* x_b    = (const float*)d_in[1];
    const int*   ei_ab  = (const int*)d_in[2];
    const int*   ei_ba  = (const int*)d_in[3];
    const float* W0ab_m = (const float*)d_in[4];
    const float* b0ab   = (const float*)d_in[5];
    const float* W0ab_s = (const float*)d_in[6];
    const float* W0ba_m = (const float*)d_in[7];
    const float* b0ba   = (const float*)d_in[8];
    const float* W0ba_s = (const float*)d_in[9];
    const float* g0a    = (const float*)d_in[10];
    const float* be0a   = (const float*)d_in[11];
    const float* g0b    = (const float*)d_in[12];
    const float* be0b   = (const float*)d_in[13];
    const float* W1ab_m = (const float*)d_in[14];
    const float* b1ab   = (const float*)d_in[15];
    const float* W1ab_s = (const float*)d_in[16];
    const float* W1ba_m = (const float*)d_in[17];
    const float* b1ba   = (const float*)d_in[18];
    const float* W1ba_s = (const float*)d_in[19];

    char* ws = (char*)d_ws;
    size_t p = 0;
    auto alloc = [&](size_t bytes) -> char* {
        char* r = ws + p;
        p += (bytes + 255) & ~(size_t)255;
        return r;
    };
    unsigned short* h_a  = (unsigned short*)alloc((size_t)NN * 128 * 2);  // bf16
    unsigned short* h_b  = (unsigned short*)alloc((size_t)NN * 128 * 2);
    unsigned short* xb_a = (unsigned short*)alloc((size_t)NN * 128 * 2);  // reused as agg1_a
    unsigned short* xb_b = (unsigned short*)alloc((size_t)NN * 128 * 2);  // reused as agg1_b
    int*   off_ab  = (int*)alloc((NN + 1) * 4);
    int*   off_ba  = (int*)alloc((NN + 1) * 4);
    int*   cnt_ab  = (int*)alloc(NN * 4);   // reused as scatter cursor
    int*   cnt_ba  = (int*)alloc(NN * 4);
    int*   srcs_ab = (int*)alloc((size_t)EE * 4);
    int*   srcs_ba = (int*)alloc((size_t)EE * 4);
    int*   bcur    = (int*)alloc((size_t)NB * 16 * 4);
    int*   part_ab = (int*)alloc(1024);
    int*   part_ba = (int*)alloc(1024);
    unsigned short* Wt = (unsigned short*)alloc((size_t)8 * 16384 * 2);
    float* bnpart  = (float*)alloc(200 * 256 * 4);
    float* stat    = (float*)alloc(256 * 4);

    // tmp pair buffer aliases h region (dead until layer-0 GEMM, after CSR done)
    uint2* tmp = (uint2*)h_a;  // 12.8 MB <= 25.6 MB

    // layer-0 agg buffers (bf16) live in d_out (102 MB fp32, unused until L1 GEMM)
    uint32* agg0_a = (uint32*)d_out;
    uint32* agg0_b = (uint32*)((char*)d_out + (size_t)NN * 128 * 2);
    uint32* agg1_a = (uint32*)xb_a;
    uint32* agg1_b = (uint32*)xb_b;

    // ---- prep: bf16 conversions ----
    f2b_kernel<<<6250, 256, 0, stream>>>(x_a, xb_a, NN * 128 / 8);
    f2b_kernel<<<6250, 256, 0, stream>>>(x_b, xb_b, NN * 128 / 8);
    prep_w<<<dim3(64, 8), 256, 0, stream>>>(W0ab_m, W0ab_s, W0ba_m, W0ba_s,
                                            W1ab_m, W1ab_s, W1ba_m, W1ba_s, Wt);
    unsigned short* Wt0ab_m = Wt;
    unsigned short* Wt0ab_s = Wt + 16384;
    unsigned short* Wt0ba_m = Wt + 2 * 16384;
    unsigned short* Wt0ba_s = Wt + 3 * 16384;
    unsigned short* Wt1ab_m = Wt + 4 * 16384;
    unsigned short* Wt1ab_s = Wt + 5 * 16384;
    unsigned short* Wt1ba_m = Wt + 6 * 16384;
    unsigned short* Wt1ba_s = Wt + 7 * 16384;

    // ---- CSR build (both directions), 2-pass bucketed scatter ----
    hipMemsetAsync(cnt_ab, 0, NN * 4, stream);
    hipMemsetAsync(cnt_ba, 0, NN * 4, stream);
    hist_kernel<<<6250, 256, 0, stream>>>(ei_ab, cnt_ab, EE);
    hist_kernel<<<6250, 256, 0, stream>>>(ei_ba, cnt_ba, EE);
    scan1<<<98, 256, 0, stream>>>(cnt_ab, part_ab, NN);
    scan1<<<98, 256, 0, stream>>>(cnt_ba, part_ba, NN);
    scan2<<<1, 128, 0, stream>>>(part_ab, off_ab + NN, 98);
    scan2<<<1, 128, 0, stream>>>(part_ba, off_ba + NN, 98);
    scan3<<<98, 256, 0, stream>>>(cnt_ab, part_ab, off_ab, NN);
    scan3<<<98, 256, 0, stream>>>(cnt_ba, part_ba, off_ba, NN);
    hipMemcpyAsync(cnt_ab, off_ab, NN * 4, hipMemcpyDeviceToDevice, stream);
    hipMemcpyAsync(cnt_ba, off_ba, NN * 4, hipMemcpyDeviceToDevice, stream);
    // ab direction
    bcur_init<<<13, 256, 0, stream>>>(off_ab, bcur);
    bucketA<<<6250, 256, 0, stream>>>(ei_ab, bcur, tmp, EE);
    bucketB<<<6250, 256, 0, stream>>>(tmp, cnt_ab, srcs_ab, EE);
    // ba direction
    bcur_init<<<13, 256, 0, stream>>>(off_ba, bcur);
    bucketA<<<6250, 256, 0, stream>>>(ei_ba, bcur, tmp, EE);
    bucketB<<<6250, 256, 0, stream>>>(tmp, cnt_ba, srcs_ba, EE);

    // ---- layer 0 ----
    agg_kernel<<<25000, 256, 0, stream>>>((const uint32*)xb_b, srcs_ba, off_ba, agg0_a, NN);
    agg_kernel<<<25000, 256, 0, stream>>>((const uint32*)xb_a, srcs_ab, off_ab, agg0_b, NN);
    gemm_bf16<true><<<782, 256, 0, stream>>>((const unsigned short*)agg0_a, xb_a,
                                             Wt0ba_m, Wt0ba_s, b0ba, h_a, NN);
    gemm_bf16<true><<<782, 256, 0, stream>>>((const unsigned short*)agg0_b, xb_b,
                                             Wt0ab_m, Wt0ab_s, b0ab, h_b, NN);
    bn_stats<<<200, 256, 0, stream>>>((const uint32*)h_a, bnpart, NN);
    bn_reduce<<<1, 256, 0, stream>>>(bnpart, stat, 200);
    bn_apply<<<25000, 256, 0, stream>>>((uint32*)h_a, stat, g0a, be0a, NN);
    bn_stats<<<200, 256, 0, stream>>>((const uint32*)h_b, bnpart, NN);
    bn_reduce<<<1, 256, 0, stream>>>(bnpart, stat, 200);
    bn_apply<<<25000, 256, 0, stream>>>((uint32*)h_b, stat, g0b, be0b, NN);

    // ---- layer 1 ----
    agg_kernel<<<25000, 256, 0, stream>>>((const uint32*)h_b, srcs_ba, off_ba, agg1_a, NN);
    agg_kernel<<<25000, 256, 0, stream>>>((const uint32*)h_a, srcs_ab, off_ab, agg1_b, NN);
    gemm_bf16<false><<<782, 256, 0, stream>>>((const unsigned short*)agg1_a, h_a,
                                              Wt1ba_m, Wt1ba_s, b1ba, (float*)d_out, NN);
    gemm_bf16<false><<<782, 256, 0, stream>>>((const unsigned short*)agg1_b, h_b,
                                              Wt1ab_m, Wt1ab_s, b1ab,
                                              (float*)d_out + (size_t)NN * 128, NN);
    l2_kernel<<<50000, 256, 0, stream>>>((float*)d_out, 2 * NN);
}